// Round 9
// baseline (163.520 us; speedup 1.0000x reference)
//
#include <hip/hip_runtime.h>
#include <hip/hip_fp16.h>
#include <climits>

// Radon forward projection (parallel beam), 512x512 image, 512 angles,
// 736 detectors x 736 samples, bilinear interpolation.
// Outputs (flat, concatenated): sino [1,512,736] then reco [1,512,512].
//
// R9 (= R8 with prep-grid fix): prep grid must be 17x17 so quad rows/cols
//     512..513 (QN=514: real row 511 + pad ring) are written — R8's 16x16
//     left them poisoned (absmax 306). Packed-fp32 2-sample inner loop,
//     shear-mapped lanes, 4-way k-split + relaxed atomics, memset/memcpy
//     for sino-zero / reco pass-through.

namespace {
constexpr int H = 512, W = 512, NA = 512, ND = 736, NS = 736;
constexpr int SINO_SIZE = NA * ND;
constexpr int IMG_SIZE = H * W;
// Quad array: entry (ri,ci), ri,ci in [0,513]:
//   q.x = (v(ri-1,ci-1), v(ri,ci-1))   column pair at ci-1
//   q.y = (v(ri-1,ci),   v(ri,ci))     column pair at ci
// zero outside [0,512)^2. Sample coords shifted +1 -> clamp domain [0,513].
constexpr int QN = 514;
constexpr int QS = 520;                 // row stride in quads (8 B each)
constexpr int QUAD_SIZE = QN * QS;
constexpr int KSPLIT = 4;
}

typedef __fp16 h2 __attribute__((ext_vector_type(2)));
typedef float  f2 __attribute__((ext_vector_type(2)));

// ---------- prep: quad layouts (both orientations), 32x8 block, 17x17 grid -
__global__ __launch_bounds__(256) void prep_quads(const float* __restrict__ x,
                                                  const float* __restrict__ reco,
                                                  uint2* __restrict__ Q,
                                                  uint2* __restrict__ QT) {
    __shared__ float tile[34][35];
    const int tx = threadIdx.x, ty = threadIdx.y;      // 32x8
    const int r0 = blockIdx.y * 32, c0 = blockIdx.x * 32;

    // Load 34x34 halo tile: cell (yy,xx) = v(r0-1+yy, c0-1+xx), 0 outside.
    for (int li = ty * 32 + tx; li < 34 * 34; li += 256) {
        const int yy = li / 34, xx = li - yy * 34;
        const int r = r0 - 1 + yy, c = c0 - 1 + xx;
        float v = 0.f;
        if ((unsigned)r < 512u && (unsigned)c < 512u) {
            const int i = r * W + c;
            v = x[i] + reco[i];
        }
        tile[yy][xx] = v;
    }
    __syncthreads();

    #pragma unroll
    for (int kk = 0; kk < 4; ++kk) {
        const int t2 = ty + 8 * kk;
        // Q quad (column pairs)
        const int ri = r0 + t2, ci = c0 + tx;
        if (ri < QN && ci < QN) {
            uint2 q;
            q.x = __builtin_bit_cast(unsigned int,
                  __builtin_amdgcn_cvt_pkrtz(tile[t2][tx],     tile[t2 + 1][tx]));
            q.y = __builtin_bit_cast(unsigned int,
                  __builtin_amdgcn_cvt_pkrtz(tile[t2][tx + 1], tile[t2 + 1][tx + 1]));
            Q[ri * QS + ci] = q;
        }
        // Transposed-image quad at transposed block location.
        const int ri2 = c0 + t2, ci2 = r0 + tx;
        if (ri2 < QN && ci2 < QN) {
            uint2 q;
            q.x = __builtin_bit_cast(unsigned int,
                  __builtin_amdgcn_cvt_pkrtz(tile[tx][t2],     tile[tx][t2 + 1]));
            q.y = __builtin_bit_cast(unsigned int,
                  __builtin_amdgcn_cvt_pkrtz(tile[tx + 1][t2], tile[tx + 1][t2 + 1]));
            QT[ri2 * QS + ci2] = q;
        }
    }
}

// Per-dim k-range for p0 + k*inc in [lo, hi].
__device__ inline void range1(float p0, float inc, float lo, float hi,
                              float& klo, float& khi) {
    if (inc > 1e-6f)       { klo = (lo - p0) / inc; khi = (hi - p0) / inc; }
    else if (inc < -1e-6f) { klo = (hi - p0) / inc; khi = (lo - p0) / inc; }
    else if (p0 >= lo && p0 <= hi) { klo = -1e9f; khi = 1e9f; }
    else                   { klo = 1e9f;  khi = -1e9f; }
}

// Wave = 64 consecutive detectors, shear-mapped k; blockIdx.z = k-quarter.
__global__ __launch_bounds__(128) void proj_quad(const uint2* __restrict__ Q,
                                                 const uint2* __restrict__ QT,
                                                 const float* __restrict__ angles,
                                                 float* __restrict__ sino) {
    const int lane = threadIdx.x & 63;
    const int d = blockIdx.x * 128 + (threadIdx.x >> 6) * 64 + lane;
    const int a = blockIdx.y;
    const int z = blockIdx.z;

    float si, co;
    sincosf(angles[a], &si, &co);

    const float cx = (W - 1) * 0.5f, cy = (H - 1) * 0.5f;
    const float s  = (float)d - (ND - 1) * 0.5f;
    const float bx = fmaf(s, co, cx);    // px = bx - t*si
    const float by = fmaf(s, si, cy);    // py = by + t*c

    // Orientation: slow dim = row dim of chosen layout; |sl| >= 0.707.
    const uint2* base;
    float f0, fi, s0, sl, dS;
    if (fabsf(co) >= fabsf(si)) { base = Q;  f0 = bx; fi = -si; s0 = by; sl = co;  dS = si; }
    else                        { base = QT; f0 = by; fi = co;  s0 = bx; sl = -si; dS = co; }

    const float t0 = -(float)(NS - 1) * 0.5f;
    float F0 = fmaf(t0, fi, f0);
    float S0 = fmaf(t0, sl, s0);
    if (sl < 0.f) {   // make slow step positive (reverses sum order only)
        F0 = fmaf((float)(NS - 1), fi, F0); fi = -fi;
        S0 = fmaf((float)(NS - 1), sl, S0); sl = -sl;
    }

    // Valid k range (conservative; clamp handles out-of-window samples).
    float kloF, khiF, kloS, khiS;
    range1(F0, fi, -0.9999f, 511.9999f, kloF, khiF);
    range1(S0, sl, -0.9999f, 511.9999f, kloS, khiS);
    const int kA = max(0,      (int)ceilf(fmaxf(kloF, kloS)));
    const int kB = min(NS - 1, (int)floorf(fminf(khiF, khiS)));

    // Shear offset: aligns slow coords across lanes at fixed loop index j.
    const int o = (int)rintf(-(float)lane * dS / sl);
    // +1 shift folds the pad-ring offset into the clamp domain [0, 513].
    const float F1 = fmaf((float)o, fi, F0) + 1.f;
    const float S1 = fmaf((float)o, sl, S0) + 1.f;

    int jA, jB;
    if (kA <= kB) { jA = kA - o; jB = kB - o; }
    else          { jA = INT_MAX; jB = INT_MIN; }
    int Jlo = jA, Jhi = jB;
    #pragma unroll
    for (int off = 1; off < 64; off <<= 1) {
        Jlo = min(Jlo, __shfl_xor(Jlo, off));
        Jhi = max(Jhi, __shfl_xor(Jhi, off));
    }
    if (Jlo > Jhi) return;                 // whole wave empty
    const int L  = Jhi - Jlo + 1;
    // Wave-uniform bounds -> scalar registers for scalar loop control.
    const int js = __builtin_amdgcn_readfirstlane(Jlo + (L * z) / KSPLIT);
    const int je = __builtin_amdgcn_readfirstlane(Jlo + (L * (z + 1)) / KSPLIT - 1);

    // Packed 2-sample loop. Overshooting je by one sample is safe: the clamp
    // sends out-of-window samples into the zero pad ring (fx/fy land on the
    // zero element).
    const f2 fi2 = {fi, fi}, sl2 = {sl, sl};
    const f2 F12 = {F1, F1}, S12 = {S1, S1};
    f2 jf2 = {(float)js, (float)(js + 1)};
    float acc0 = 0.f, acc1 = 0.f;
    for (int j = js; j <= je; j += 2) {
        f2 pf = jf2 * fi2 + F12;           // v_pk_fma_f32
        f2 ps = jf2 * sl2 + S12;
        jf2 += (f2)2.f;
        pf = __builtin_elementwise_min(__builtin_elementwise_max(pf, (f2)0.f), (f2)513.f);
        ps = __builtin_elementwise_min(__builtin_elementwise_max(ps, (f2)0.f), (f2)513.f);
        const f2 ff = {__builtin_floorf(pf.x), __builtin_floorf(pf.y)};
        const f2 sf = {__builtin_floorf(ps.x), __builtin_floorf(ps.y)};
        const f2 fx = pf - ff;
        const f2 fy = ps - sf;
        const f2 gy = (f2)1.f - fy;
        const f2 aif = sf * (f2)520.f + ff;      // exact (< 2^24)
        const int a0 = (int)aif.x, a1 = (int)aif.y;
        const uint2 q0 = base[a0];
        const uint2 q1 = base[a1];
        // sample 0
        {
            const h2 l = __builtin_bit_cast(h2, q0.x);   // (v00, v10)
            const h2 r = __builtin_bit_cast(h2, q0.y);   // (v01, v11)
            const h2 fxx = __builtin_amdgcn_cvt_pkrtz(fx.x, fx.x);
            const h2 m = l + fxx * (r - l);
            const h2 wy = __builtin_amdgcn_cvt_pkrtz(gy.x, fy.x);
#if __has_builtin(__builtin_amdgcn_fdot2)
            acc0 = __builtin_amdgcn_fdot2(wy, m, acc0, false);
#else
            acc0 += (float)wy.x * (float)m.x + (float)wy.y * (float)m.y;
#endif
        }
        // sample 1
        {
            const h2 l = __builtin_bit_cast(h2, q1.x);
            const h2 r = __builtin_bit_cast(h2, q1.y);
            const h2 fxx = __builtin_amdgcn_cvt_pkrtz(fx.y, fx.y);
            const h2 m = l + fxx * (r - l);
            const h2 wy = __builtin_amdgcn_cvt_pkrtz(gy.y, fy.y);
#if __has_builtin(__builtin_amdgcn_fdot2)
            acc1 = __builtin_amdgcn_fdot2(wy, m, acc1, false);
#else
            acc1 += (float)wy.x * (float)m.x + (float)wy.y * (float)m.y;
#endif
        }
    }
    const float acc = acc0 + acc1;
    if (d < ND)
        __hip_atomic_fetch_add(&sino[a * ND + d], acc,
                               __ATOMIC_RELAXED, __HIP_MEMORY_SCOPE_AGENT);
}

// ================= fallback (tiny ws): fused fp32 ==========================
__global__ __launch_bounds__(256) void proj_fused(const float* __restrict__ A,
                                                  const float* __restrict__ B,
                                                  const float* __restrict__ angles,
                                                  float* __restrict__ sino) {
    const int d = blockIdx.x * blockDim.x + threadIdx.x;
    const int a = blockIdx.y;
    if (d >= ND) return;
    float si, c;
    sincosf(angles[a], &si, &c);
    const float cx = (W - 1) * 0.5f, cy = (H - 1) * 0.5f;
    const float s  = (float)d - (ND - 1) * 0.5f;
    const float bx = fmaf(s, c, cx), by = fmaf(s, si, cy);
    const float t0 = -(float)(NS - 1) * 0.5f;
    float acc = 0.f;
    for (int k = 0; k < NS; ++k) {
        const float t = t0 + (float)k;
        const float px = fmaf(t, -si, bx), py = fmaf(t, c, by);
        const float x0f = floorf(px), y0f = floorf(py);
        const float fx = px - x0f, fy = py - y0f;
        const int ix = (int)x0f, iy = (int)y0f;
        auto tap = [&](int yi, int xi) -> float {
            if (xi < 0 || xi >= W || yi < 0 || yi >= H) return 0.f;
            return A[yi * W + xi] + B[yi * W + xi];
        };
        float v = 0.f;
        if (ix >= -1 && iy >= -1 && ix <= W - 1 && iy <= H - 1) {
            const float v00 = tap(iy, ix),     v01 = tap(iy, ix + 1);
            const float v10 = tap(iy + 1, ix), v11 = tap(iy + 1, ix + 1);
            const float top = fmaf(fx, v01 - v00, v00);
            const float bot = fmaf(fx, v11 - v10, v10);
            v = fmaf(fy, bot - top, top);
        }
        acc += v;
    }
    sino[a * ND + d] = acc;
}

__global__ void prep_copy(const float* __restrict__ reco, float* __restrict__ reco_out) {
    int i = blockIdx.x * blockDim.x + threadIdx.x;
    if (i < IMG_SIZE) reco_out[i] = reco[i];
}

extern "C" void kernel_launch(void* const* d_in, const int* in_sizes, int n_in,
                              void* d_out, int out_size, void* d_ws, size_t ws_size,
                              hipStream_t stream) {
    const float* x      = (const float*)d_in[0];
    const float* reco   = (const float*)d_in[1];
    const float* angles = (const float*)d_in[2];
    float* sino     = (float*)d_out;
    float* reco_out = sino + SINO_SIZE;

    const size_t need_quads = 2 * (size_t)QUAD_SIZE * sizeof(uint2);    // ~4.28 MiB

    if (ws_size >= need_quads) {
        uint2* Q  = (uint2*)d_ws;
        uint2* QT = Q + QUAD_SIZE;
        hipMemsetAsync(sino, 0, (size_t)SINO_SIZE * sizeof(float), stream);
        hipMemcpyAsync(reco_out, reco, (size_t)IMG_SIZE * sizeof(float),
                       hipMemcpyDeviceToDevice, stream);
        // 17x17 grid: quad indices up to 543 so rows/cols 512..513 (< QN=514)
        // are written — 16x16 leaves them poisoned (R8 bug).
        prep_quads<<<dim3(17, 17), dim3(32, 8), 0, stream>>>(x, reco, Q, QT);
        proj_quad<<<dim3(6, NA, KSPLIT), dim3(128), 0, stream>>>(Q, QT, angles, sino);
    } else {
        prep_copy<<<dim3((IMG_SIZE + 255) / 256), dim3(256), 0, stream>>>(reco, reco_out);
        proj_fused<<<dim3((ND + 255) / 256, NA), dim3(256), 0, stream>>>(x, reco, angles, sino);
    }
}

// Round 10
// 155.938 us; speedup vs baseline: 1.0486x; 1.0486x over previous
//
#include <hip/hip_runtime.h>
#include <hip/hip_fp16.h>
#include <climits>

// Radon forward projection (parallel beam), 512x512 image, 512 angles,
// 736 detectors x 736 samples, bilinear interpolation.
// Outputs (flat, concatenated): sino [1,512,736] then reco [1,512,512].
//
// R10: fix R9's pair-overshoot double-count (overshoot sample belongs to the
//      NEXT k-quarter -> counted twice; absmax 8.0). Even-pair loop + scalar
//      odd tail. Fold reco pass-through into prep (drop memcpy node).
//      unroll 2 on the packed loop for load pipelining.

namespace {
constexpr int H = 512, W = 512, NA = 512, ND = 736, NS = 736;
constexpr int SINO_SIZE = NA * ND;
constexpr int IMG_SIZE = H * W;
// Quad array: entry (ri,ci), ri,ci in [0,513]:
//   q.x = (v(ri-1,ci-1), v(ri,ci-1))   column pair at ci-1
//   q.y = (v(ri-1,ci),   v(ri,ci))     column pair at ci
// zero outside [0,512)^2. Sample coords shifted +1 -> clamp domain [0,513].
constexpr int QN = 514;
constexpr int QS = 520;                 // row stride in quads (8 B each)
constexpr int QUAD_SIZE = QN * QS;
constexpr int KSPLIT = 4;
}

typedef __fp16 h2 __attribute__((ext_vector_type(2)));
typedef float  f2 __attribute__((ext_vector_type(2)));

// ---------- prep: quad layouts + reco pass-through; 32x8 block, 17x17 grid -
__global__ __launch_bounds__(256) void prep_quads(const float* __restrict__ x,
                                                  const float* __restrict__ reco,
                                                  uint2* __restrict__ Q,
                                                  uint2* __restrict__ QT,
                                                  float* __restrict__ reco_out) {
    __shared__ float tile[34][35];
    const int tx = threadIdx.x, ty = threadIdx.y;      // 32x8
    const int r0 = blockIdx.y * 32, c0 = blockIdx.x * 32;

    // Load 34x34 halo tile: cell (yy,xx) = v(r0-1+yy, c0-1+xx), 0 outside.
    for (int li = ty * 32 + tx; li < 34 * 34; li += 256) {
        const int yy = li / 34, xx = li - yy * 34;
        const int r = r0 - 1 + yy, c = c0 - 1 + xx;
        float v = 0.f;
        if ((unsigned)r < 512u && (unsigned)c < 512u) {
            const int i = r * W + c;
            v = x[i] + reco[i];
        }
        tile[yy][xx] = v;
    }
    __syncthreads();

    #pragma unroll
    for (int kk = 0; kk < 4; ++kk) {
        const int t2 = ty + 8 * kk;
        // Q quad (column pairs)
        const int ri = r0 + t2, ci = c0 + tx;
        if (ri < QN && ci < QN) {
            uint2 q;
            q.x = __builtin_bit_cast(unsigned int,
                  __builtin_amdgcn_cvt_pkrtz(tile[t2][tx],     tile[t2 + 1][tx]));
            q.y = __builtin_bit_cast(unsigned int,
                  __builtin_amdgcn_cvt_pkrtz(tile[t2][tx + 1], tile[t2 + 1][tx + 1]));
            Q[ri * QS + ci] = q;
        }
        // Transposed-image quad at transposed block location.
        const int ri2 = c0 + t2, ci2 = r0 + tx;
        if (ri2 < QN && ci2 < QN) {
            uint2 q;
            q.x = __builtin_bit_cast(unsigned int,
                  __builtin_amdgcn_cvt_pkrtz(tile[tx][t2],     tile[tx][t2 + 1]));
            q.y = __builtin_bit_cast(unsigned int,
                  __builtin_amdgcn_cvt_pkrtz(tile[tx + 1][t2], tile[tx + 1][t2 + 1]));
            QT[ri2 * QS + ci2] = q;
        }
        // reco pass-through (coalesced 4B/lane)
        const int rr = r0 + t2, cc = c0 + tx;
        if (rr < H && cc < W) reco_out[rr * W + cc] = reco[rr * W + cc];
    }
}

// Per-dim k-range for p0 + k*inc in [lo, hi].
__device__ inline void range1(float p0, float inc, float lo, float hi,
                              float& klo, float& khi) {
    if (inc > 1e-6f)       { klo = (lo - p0) / inc; khi = (hi - p0) / inc; }
    else if (inc < -1e-6f) { klo = (hi - p0) / inc; khi = (lo - p0) / inc; }
    else if (p0 >= lo && p0 <= hi) { klo = -1e9f; khi = 1e9f; }
    else                   { klo = 1e9f;  khi = -1e9f; }
}

// Wave = 64 consecutive detectors, shear-mapped k; blockIdx.z = k-quarter.
__global__ __launch_bounds__(128) void proj_quad(const uint2* __restrict__ Q,
                                                 const uint2* __restrict__ QT,
                                                 const float* __restrict__ angles,
                                                 float* __restrict__ sino) {
    const int lane = threadIdx.x & 63;
    const int d = blockIdx.x * 128 + (threadIdx.x >> 6) * 64 + lane;
    const int a = blockIdx.y;
    const int z = blockIdx.z;

    float si, co;
    sincosf(angles[a], &si, &co);

    const float cx = (W - 1) * 0.5f, cy = (H - 1) * 0.5f;
    const float s  = (float)d - (ND - 1) * 0.5f;
    const float bx = fmaf(s, co, cx);    // px = bx - t*si
    const float by = fmaf(s, si, cy);    // py = by + t*c

    // Orientation: slow dim = row dim of chosen layout; |sl| >= 0.707.
    const uint2* base;
    float f0, fi, s0, sl, dS;
    if (fabsf(co) >= fabsf(si)) { base = Q;  f0 = bx; fi = -si; s0 = by; sl = co;  dS = si; }
    else                        { base = QT; f0 = by; fi = co;  s0 = bx; sl = -si; dS = co; }

    const float t0 = -(float)(NS - 1) * 0.5f;
    float F0 = fmaf(t0, fi, f0);
    float S0 = fmaf(t0, sl, s0);
    if (sl < 0.f) {   // make slow step positive (reverses sum order only)
        F0 = fmaf((float)(NS - 1), fi, F0); fi = -fi;
        S0 = fmaf((float)(NS - 1), sl, S0); sl = -sl;
    }

    // Valid k range (conservative; clamp handles boundary rounding).
    float kloF, khiF, kloS, khiS;
    range1(F0, fi, -0.9999f, 511.9999f, kloF, khiF);
    range1(S0, sl, -0.9999f, 511.9999f, kloS, khiS);
    const int kA = max(0,      (int)ceilf(fmaxf(kloF, kloS)));
    const int kB = min(NS - 1, (int)floorf(fminf(khiF, khiS)));

    // Shear offset: aligns slow coords across lanes at fixed loop index j.
    const int o = (int)rintf(-(float)lane * dS / sl);
    // +1 shift folds the pad-ring offset into the clamp domain [0, 513].
    const float F1 = fmaf((float)o, fi, F0) + 1.f;
    const float S1 = fmaf((float)o, sl, S0) + 1.f;

    int jA, jB;
    if (kA <= kB) { jA = kA - o; jB = kB - o; }
    else          { jA = INT_MAX; jB = INT_MIN; }
    int Jlo = jA, Jhi = jB;
    #pragma unroll
    for (int off = 1; off < 64; off <<= 1) {
        Jlo = min(Jlo, __shfl_xor(Jlo, off));
        Jhi = max(Jhi, __shfl_xor(Jhi, off));
    }
    if (Jlo > Jhi) return;                 // whole wave empty
    const int L  = Jhi - Jlo + 1;
    // Wave-uniform bounds -> scalar registers for scalar loop control.
    const int js = __builtin_amdgcn_readfirstlane(Jlo + (L * z) / KSPLIT);
    const int je = __builtin_amdgcn_readfirstlane(Jlo + (L * (z + 1)) / KSPLIT - 1);
    const int n  = je - js + 1;            // may be <= 0 for tiny L
    // Even part [js, je2], then optional single tail at je. NO overshoot:
    // overshooting je would double-count the next z-quarter's first sample.
    const int je2 = js + 2 * (n >> 1) - 1;

    const f2 fi2 = {fi, fi}, sl2 = {sl, sl};
    const f2 F12 = {F1, F1}, S12 = {S1, S1};
    f2 jf2 = {(float)js, (float)(js + 1)};
    float acc0 = 0.f, acc1 = 0.f;
    #pragma unroll 2
    for (int j = js; j <= je2; j += 2) {
        f2 pf = jf2 * fi2 + F12;           // v_pk_fma_f32
        f2 ps = jf2 * sl2 + S12;
        jf2 += (f2)2.f;
        pf = __builtin_elementwise_min(__builtin_elementwise_max(pf, (f2)0.f), (f2)513.f);
        ps = __builtin_elementwise_min(__builtin_elementwise_max(ps, (f2)0.f), (f2)513.f);
        const f2 ff = {__builtin_floorf(pf.x), __builtin_floorf(pf.y)};
        const f2 sf = {__builtin_floorf(ps.x), __builtin_floorf(ps.y)};
        const f2 fx = pf - ff;
        const f2 fy = ps - sf;
        const f2 gy = (f2)1.f - fy;
        const f2 aif = sf * (f2)520.f + ff;      // exact (< 2^24)
        const int a0 = (int)aif.x, a1 = (int)aif.y;
        const uint2 q0 = base[a0];
        const uint2 q1 = base[a1];
        {
            const h2 l = __builtin_bit_cast(h2, q0.x);   // (v00, v10)
            const h2 r = __builtin_bit_cast(h2, q0.y);   // (v01, v11)
            const h2 fxx = __builtin_amdgcn_cvt_pkrtz(fx.x, fx.x);
            const h2 m = l + fxx * (r - l);
            const h2 wy = __builtin_amdgcn_cvt_pkrtz(gy.x, fy.x);
#if __has_builtin(__builtin_amdgcn_fdot2)
            acc0 = __builtin_amdgcn_fdot2(wy, m, acc0, false);
#else
            acc0 += (float)wy.x * (float)m.x + (float)wy.y * (float)m.y;
#endif
        }
        {
            const h2 l = __builtin_bit_cast(h2, q1.x);
            const h2 r = __builtin_bit_cast(h2, q1.y);
            const h2 fxx = __builtin_amdgcn_cvt_pkrtz(fx.y, fx.y);
            const h2 m = l + fxx * (r - l);
            const h2 wy = __builtin_amdgcn_cvt_pkrtz(gy.y, fy.y);
#if __has_builtin(__builtin_amdgcn_fdot2)
            acc1 = __builtin_amdgcn_fdot2(wy, m, acc1, false);
#else
            acc1 += (float)wy.x * (float)m.x + (float)wy.y * (float)m.y;
#endif
        }
    }
    if (n & 1) {   // single tail sample at je (scalar)
        const float jf = (float)je;
        float pf = fmaf(jf, fi, F1);
        float ps = fmaf(jf, sl, S1);
        pf = fminf(fmaxf(pf, 0.f), 513.f);
        ps = fminf(fmaxf(ps, 0.f), 513.f);
        const float ff = floorf(pf), sf = floorf(ps);
        const float fx = pf - ff,   fy = ps - sf;
        const int ai = (int)fmaf(sf, 520.f, ff);
        const uint2 q = base[ai];
        const h2 l = __builtin_bit_cast(h2, q.x);
        const h2 r = __builtin_bit_cast(h2, q.y);
        const h2 fxx = __builtin_amdgcn_cvt_pkrtz(fx, fx);
        const h2 m = l + fxx * (r - l);
        const h2 wy = __builtin_amdgcn_cvt_pkrtz(1.f - fy, fy);
#if __has_builtin(__builtin_amdgcn_fdot2)
        acc0 = __builtin_amdgcn_fdot2(wy, m, acc0, false);
#else
        acc0 += (float)wy.x * (float)m.x + (float)wy.y * (float)m.y;
#endif
    }
    const float acc = acc0 + acc1;
    if (d < ND)
        __hip_atomic_fetch_add(&sino[a * ND + d], acc,
                               __ATOMIC_RELAXED, __HIP_MEMORY_SCOPE_AGENT);
}

// ================= fallback (tiny ws): fused fp32 ==========================
__global__ __launch_bounds__(256) void proj_fused(const float* __restrict__ A,
                                                  const float* __restrict__ B,
                                                  const float* __restrict__ angles,
                                                  float* __restrict__ sino) {
    const int d = blockIdx.x * blockDim.x + threadIdx.x;
    const int a = blockIdx.y;
    if (d >= ND) return;
    float si, c;
    sincosf(angles[a], &si, &c);
    const float cx = (W - 1) * 0.5f, cy = (H - 1) * 0.5f;
    const float s  = (float)d - (ND - 1) * 0.5f;
    const float bx = fmaf(s, c, cx), by = fmaf(s, si, cy);
    const float t0 = -(float)(NS - 1) * 0.5f;
    float acc = 0.f;
    for (int k = 0; k < NS; ++k) {
        const float t = t0 + (float)k;
        const float px = fmaf(t, -si, bx), py = fmaf(t, c, by);
        const float x0f = floorf(px), y0f = floorf(py);
        const float fx = px - x0f, fy = py - y0f;
        const int ix = (int)x0f, iy = (int)y0f;
        auto tap = [&](int yi, int xi) -> float {
            if (xi < 0 || xi >= W || yi < 0 || yi >= H) return 0.f;
            return A[yi * W + xi] + B[yi * W + xi];
        };
        float v = 0.f;
        if (ix >= -1 && iy >= -1 && ix <= W - 1 && iy <= H - 1) {
            const float v00 = tap(iy, ix),     v01 = tap(iy, ix + 1);
            const float v10 = tap(iy + 1, ix), v11 = tap(iy + 1, ix + 1);
            const float top = fmaf(fx, v01 - v00, v00);
            const float bot = fmaf(fx, v11 - v10, v10);
            v = fmaf(fy, bot - top, top);
        }
        acc += v;
    }
    sino[a * ND + d] = acc;
}

__global__ void prep_copy(const float* __restrict__ reco, float* __restrict__ reco_out) {
    int i = blockIdx.x * blockDim.x + threadIdx.x;
    if (i < IMG_SIZE) reco_out[i] = reco[i];
}

extern "C" void kernel_launch(void* const* d_in, const int* in_sizes, int n_in,
                              void* d_out, int out_size, void* d_ws, size_t ws_size,
                              hipStream_t stream) {
    const float* x      = (const float*)d_in[0];
    const float* reco   = (const float*)d_in[1];
    const float* angles = (const float*)d_in[2];
    float* sino     = (float*)d_out;
    float* reco_out = sino + SINO_SIZE;

    const size_t need_quads = 2 * (size_t)QUAD_SIZE * sizeof(uint2);    // ~4.28 MiB

    if (ws_size >= need_quads) {
        uint2* Q  = (uint2*)d_ws;
        uint2* QT = Q + QUAD_SIZE;
        hipMemsetAsync(sino, 0, (size_t)SINO_SIZE * sizeof(float), stream);
        // 17x17 grid: quad indices up to 543 so rows/cols 512..513 (< QN=514)
        // are written — 16x16 leaves them poisoned (R8 bug).
        prep_quads<<<dim3(17, 17), dim3(32, 8), 0, stream>>>(x, reco, Q, QT, reco_out);
        proj_quad<<<dim3(6, NA, KSPLIT), dim3(128), 0, stream>>>(Q, QT, angles, sino);
    } else {
        prep_copy<<<dim3((IMG_SIZE + 255) / 256), dim3(256), 0, stream>>>(reco, reco_out);
        proj_fused<<<dim3((ND + 255) / 256, NA), dim3(256), 0, stream>>>(x, reco, angles, sino);
    }
}

// Round 11
// 149.462 us; speedup vs baseline: 1.0941x; 1.0433x over previous
//
#include <hip/hip_runtime.h>
#include <hip/hip_fp16.h>
#include <climits>

// Radon forward projection (parallel beam), 512x512 image, 512 angles,
// 736 detectors x 736 samples, bilinear interpolation.
// Outputs (flat, concatenated): sino [1,512,736] then reco [1,512,512].
//
// R11: KSPLIT 8 (finer chunks -> less imbalance tail; occupancy was 62%),
//      sino zeroing folded into prep (2 graph nodes), unsigned 32-bit quad
//      offsets (saddr-form global loads, fewer addr VALU ops). Otherwise
//      identical to R10 (packed-fp32 2-sample loop, even-pair + odd tail,
//      shear-mapped lanes, relaxed atomics).

namespace {
constexpr int H = 512, W = 512, NA = 512, ND = 736, NS = 736;
constexpr int SINO_SIZE = NA * ND;
constexpr int IMG_SIZE = H * W;
// Quad array: entry (ri,ci), ri,ci in [0,513]:
//   q.x = (v(ri-1,ci-1), v(ri,ci-1))   column pair at ci-1
//   q.y = (v(ri-1,ci),   v(ri,ci))     column pair at ci
// zero outside [0,512)^2. Sample coords shifted +1 -> clamp domain [0,513].
constexpr int QN = 514;
constexpr int QS = 520;                 // row stride in quads (8 B each)
constexpr int QUAD_SIZE = QN * QS;
constexpr int KSPLIT = 8;
}

typedef __fp16 h2 __attribute__((ext_vector_type(2)));
typedef float  f2 __attribute__((ext_vector_type(2)));

// ---------- prep: quads + reco pass-through + sino zero; 17x17 grid --------
__global__ __launch_bounds__(256) void prep_quads(const float* __restrict__ x,
                                                  const float* __restrict__ reco,
                                                  uint2* __restrict__ Q,
                                                  uint2* __restrict__ QT,
                                                  float* __restrict__ reco_out,
                                                  float* __restrict__ sino) {
    __shared__ float tile[34][35];
    const int tx = threadIdx.x, ty = threadIdx.y;      // 32x8
    const int r0 = blockIdx.y * 32, c0 = blockIdx.x * 32;

    // Zero sinogram (atomically accumulated by proj; d_out is poisoned).
    {
        const int nthr = 289 * 256;
        const int gtid = (blockIdx.y * 17 + blockIdx.x) * 256 + ty * 32 + tx;
        for (int i = gtid; i < SINO_SIZE; i += nthr) sino[i] = 0.f;
    }

    // Load 34x34 halo tile: cell (yy,xx) = v(r0-1+yy, c0-1+xx), 0 outside.
    for (int li = ty * 32 + tx; li < 34 * 34; li += 256) {
        const int yy = li / 34, xx = li - yy * 34;
        const int r = r0 - 1 + yy, c = c0 - 1 + xx;
        float v = 0.f;
        if ((unsigned)r < 512u && (unsigned)c < 512u) {
            const int i = r * W + c;
            v = x[i] + reco[i];
        }
        tile[yy][xx] = v;
    }
    __syncthreads();

    #pragma unroll
    for (int kk = 0; kk < 4; ++kk) {
        const int t2 = ty + 8 * kk;
        // Q quad (column pairs)
        const int ri = r0 + t2, ci = c0 + tx;
        if (ri < QN && ci < QN) {
            uint2 q;
            q.x = __builtin_bit_cast(unsigned int,
                  __builtin_amdgcn_cvt_pkrtz(tile[t2][tx],     tile[t2 + 1][tx]));
            q.y = __builtin_bit_cast(unsigned int,
                  __builtin_amdgcn_cvt_pkrtz(tile[t2][tx + 1], tile[t2 + 1][tx + 1]));
            Q[ri * QS + ci] = q;
        }
        // Transposed-image quad at transposed block location.
        const int ri2 = c0 + t2, ci2 = r0 + tx;
        if (ri2 < QN && ci2 < QN) {
            uint2 q;
            q.x = __builtin_bit_cast(unsigned int,
                  __builtin_amdgcn_cvt_pkrtz(tile[tx][t2],     tile[tx][t2 + 1]));
            q.y = __builtin_bit_cast(unsigned int,
                  __builtin_amdgcn_cvt_pkrtz(tile[tx + 1][t2], tile[tx + 1][t2 + 1]));
            QT[ri2 * QS + ci2] = q;
        }
        // reco pass-through (coalesced 4B/lane)
        const int rr = r0 + t2, cc = c0 + tx;
        if (rr < H && cc < W) reco_out[rr * W + cc] = reco[rr * W + cc];
    }
}

// Per-dim k-range for p0 + k*inc in [lo, hi].
__device__ inline void range1(float p0, float inc, float lo, float hi,
                              float& klo, float& khi) {
    if (inc > 1e-6f)       { klo = (lo - p0) / inc; khi = (hi - p0) / inc; }
    else if (inc < -1e-6f) { klo = (hi - p0) / inc; khi = (lo - p0) / inc; }
    else if (p0 >= lo && p0 <= hi) { klo = -1e9f; khi = 1e9f; }
    else                   { klo = 1e9f;  khi = -1e9f; }
}

// Wave = 64 consecutive detectors, shear-mapped k; blockIdx.z = k-eighth.
__global__ __launch_bounds__(128) void proj_quad(const uint2* __restrict__ Q,
                                                 const uint2* __restrict__ QT,
                                                 const float* __restrict__ angles,
                                                 float* __restrict__ sino) {
    const int lane = threadIdx.x & 63;
    const int d = blockIdx.x * 128 + (threadIdx.x >> 6) * 64 + lane;
    const int a = blockIdx.y;
    const int z = blockIdx.z;

    float si, co;
    sincosf(angles[a], &si, &co);

    const float cx = (W - 1) * 0.5f, cy = (H - 1) * 0.5f;
    const float s  = (float)d - (ND - 1) * 0.5f;
    const float bx = fmaf(s, co, cx);    // px = bx - t*si
    const float by = fmaf(s, si, cy);    // py = by + t*c

    // Orientation: slow dim = row dim of chosen layout; |sl| >= 0.707.
    const uint2* base;
    float f0, fi, s0, sl, dS;
    if (fabsf(co) >= fabsf(si)) { base = Q;  f0 = bx; fi = -si; s0 = by; sl = co;  dS = si; }
    else                        { base = QT; f0 = by; fi = co;  s0 = bx; sl = -si; dS = co; }

    const float t0 = -(float)(NS - 1) * 0.5f;
    float F0 = fmaf(t0, fi, f0);
    float S0 = fmaf(t0, sl, s0);
    if (sl < 0.f) {   // make slow step positive (reverses sum order only)
        F0 = fmaf((float)(NS - 1), fi, F0); fi = -fi;
        S0 = fmaf((float)(NS - 1), sl, S0); sl = -sl;
    }

    // Valid k range (conservative; clamp handles boundary rounding).
    float kloF, khiF, kloS, khiS;
    range1(F0, fi, -0.9999f, 511.9999f, kloF, khiF);
    range1(S0, sl, -0.9999f, 511.9999f, kloS, khiS);
    const int kA = max(0,      (int)ceilf(fmaxf(kloF, kloS)));
    const int kB = min(NS - 1, (int)floorf(fminf(khiF, khiS)));

    // Shear offset: aligns slow coords across lanes at fixed loop index j.
    const int o = (int)rintf(-(float)lane * dS / sl);
    // +1 shift folds the pad-ring offset into the clamp domain [0, 513].
    const float F1 = fmaf((float)o, fi, F0) + 1.f;
    const float S1 = fmaf((float)o, sl, S0) + 1.f;

    int jA, jB;
    if (kA <= kB) { jA = kA - o; jB = kB - o; }
    else          { jA = INT_MAX; jB = INT_MIN; }
    int Jlo = jA, Jhi = jB;
    #pragma unroll
    for (int off = 1; off < 64; off <<= 1) {
        Jlo = min(Jlo, __shfl_xor(Jlo, off));
        Jhi = max(Jhi, __shfl_xor(Jhi, off));
    }
    if (Jlo > Jhi) return;                 // whole wave empty
    const int L  = Jhi - Jlo + 1;
    // Wave-uniform bounds -> scalar registers for scalar loop control.
    const int js = __builtin_amdgcn_readfirstlane(Jlo + (L * z) / KSPLIT);
    const int je = __builtin_amdgcn_readfirstlane(Jlo + (L * (z + 1)) / KSPLIT - 1);
    const int n  = je - js + 1;            // may be 0 for tiny L
    // Even part [js, je2], then optional single tail at je. NO overshoot:
    // overshooting je would double-count the next z-chunk's first sample.
    const int je2 = js + 2 * (n >> 1) - 1;

    const f2 fi2 = {fi, fi}, sl2 = {sl, sl};
    const f2 F12 = {F1, F1}, S12 = {S1, S1};
    f2 jf2 = {(float)js, (float)(js + 1)};
    float acc0 = 0.f, acc1 = 0.f;
    #pragma unroll 2
    for (int j = js; j <= je2; j += 2) {
        f2 pf = jf2 * fi2 + F12;           // v_pk_fma_f32
        f2 ps = jf2 * sl2 + S12;
        jf2 += (f2)2.f;
        pf = __builtin_elementwise_min(__builtin_elementwise_max(pf, (f2)0.f), (f2)513.f);
        ps = __builtin_elementwise_min(__builtin_elementwise_max(ps, (f2)0.f), (f2)513.f);
        const f2 ff = {__builtin_floorf(pf.x), __builtin_floorf(pf.y)};
        const f2 sf = {__builtin_floorf(ps.x), __builtin_floorf(ps.y)};
        const f2 fx = pf - ff;
        const f2 fy = ps - sf;
        const f2 gy = (f2)1.f - fy;
        const f2 aif = sf * (f2)520.f + ff;        // exact (< 2^24), >= 0
        const unsigned a0 = (unsigned)aif.x;       // unsigned 32-bit offset ->
        const unsigned a1 = (unsigned)aif.y;       // saddr-form global_load
        const uint2 q0 = base[a0];
        const uint2 q1 = base[a1];
        {
            const h2 l = __builtin_bit_cast(h2, q0.x);   // (v00, v10)
            const h2 r = __builtin_bit_cast(h2, q0.y);   // (v01, v11)
            const h2 fxx = __builtin_amdgcn_cvt_pkrtz(fx.x, fx.x);
            const h2 m = l + fxx * (r - l);
            const h2 wy = __builtin_amdgcn_cvt_pkrtz(gy.x, fy.x);
#if __has_builtin(__builtin_amdgcn_fdot2)
            acc0 = __builtin_amdgcn_fdot2(wy, m, acc0, false);
#else
            acc0 += (float)wy.x * (float)m.x + (float)wy.y * (float)m.y;
#endif
        }
        {
            const h2 l = __builtin_bit_cast(h2, q1.x);
            const h2 r = __builtin_bit_cast(h2, q1.y);
            const h2 fxx = __builtin_amdgcn_cvt_pkrtz(fx.y, fx.y);
            const h2 m = l + fxx * (r - l);
            const h2 wy = __builtin_amdgcn_cvt_pkrtz(gy.y, fy.y);
#if __has_builtin(__builtin_amdgcn_fdot2)
            acc1 = __builtin_amdgcn_fdot2(wy, m, acc1, false);
#else
            acc1 += (float)wy.x * (float)m.x + (float)wy.y * (float)m.y;
#endif
        }
    }
    if (n & 1) {   // single tail sample at je (scalar)
        const float jf = (float)je;
        float pf = fmaf(jf, fi, F1);
        float ps = fmaf(jf, sl, S1);
        pf = fminf(fmaxf(pf, 0.f), 513.f);
        ps = fminf(fmaxf(ps, 0.f), 513.f);
        const float ff = floorf(pf), sf = floorf(ps);
        const float fx = pf - ff,   fy = ps - sf;
        const unsigned ai = (unsigned)fmaf(sf, 520.f, ff);
        const uint2 q = base[ai];
        const h2 l = __builtin_bit_cast(h2, q.x);
        const h2 r = __builtin_bit_cast(h2, q.y);
        const h2 fxx = __builtin_amdgcn_cvt_pkrtz(fx, fx);
        const h2 m = l + fxx * (r - l);
        const h2 wy = __builtin_amdgcn_cvt_pkrtz(1.f - fy, fy);
#if __has_builtin(__builtin_amdgcn_fdot2)
        acc0 = __builtin_amdgcn_fdot2(wy, m, acc0, false);
#else
        acc0 += (float)wy.x * (float)m.x + (float)wy.y * (float)m.y;
#endif
    }
    const float acc = acc0 + acc1;
    if (d < ND)
        __hip_atomic_fetch_add(&sino[a * ND + d], acc,
                               __ATOMIC_RELAXED, __HIP_MEMORY_SCOPE_AGENT);
}

// ================= fallback (tiny ws): fused fp32 ==========================
__global__ __launch_bounds__(256) void proj_fused(const float* __restrict__ A,
                                                  const float* __restrict__ B,
                                                  const float* __restrict__ angles,
                                                  float* __restrict__ sino) {
    const int d = blockIdx.x * blockDim.x + threadIdx.x;
    const int a = blockIdx.y;
    if (d >= ND) return;
    float si, c;
    sincosf(angles[a], &si, &c);
    const float cx = (W - 1) * 0.5f, cy = (H - 1) * 0.5f;
    const float s  = (float)d - (ND - 1) * 0.5f;
    const float bx = fmaf(s, c, cx), by = fmaf(s, si, cy);
    const float t0 = -(float)(NS - 1) * 0.5f;
    float acc = 0.f;
    for (int k = 0; k < NS; ++k) {
        const float t = t0 + (float)k;
        const float px = fmaf(t, -si, bx), py = fmaf(t, c, by);
        const float x0f = floorf(px), y0f = floorf(py);
        const float fx = px - x0f, fy = py - y0f;
        const int ix = (int)x0f, iy = (int)y0f;
        auto tap = [&](int yi, int xi) -> float {
            if (xi < 0 || xi >= W || yi < 0 || yi >= H) return 0.f;
            return A[yi * W + xi] + B[yi * W + xi];
        };
        float v = 0.f;
        if (ix >= -1 && iy >= -1 && ix <= W - 1 && iy <= H - 1) {
            const float v00 = tap(iy, ix),     v01 = tap(iy, ix + 1);
            const float v10 = tap(iy + 1, ix), v11 = tap(iy + 1, ix + 1);
            const float top = fmaf(fx, v01 - v00, v00);
            const float bot = fmaf(fx, v11 - v10, v10);
            v = fmaf(fy, bot - top, top);
        }
        acc += v;
    }
    sino[a * ND + d] = acc;
}

__global__ void prep_copy(const float* __restrict__ reco, float* __restrict__ reco_out) {
    int i = blockIdx.x * blockDim.x + threadIdx.x;
    if (i < IMG_SIZE) reco_out[i] = reco[i];
}

extern "C" void kernel_launch(void* const* d_in, const int* in_sizes, int n_in,
                              void* d_out, int out_size, void* d_ws, size_t ws_size,
                              hipStream_t stream) {
    const float* x      = (const float*)d_in[0];
    const float* reco   = (const float*)d_in[1];
    const float* angles = (const float*)d_in[2];
    float* sino     = (float*)d_out;
    float* reco_out = sino + SINO_SIZE;

    const size_t need_quads = 2 * (size_t)QUAD_SIZE * sizeof(uint2);    // ~4.28 MiB

    if (ws_size >= need_quads) {
        uint2* Q  = (uint2*)d_ws;
        uint2* QT = Q + QUAD_SIZE;
        // 17x17 grid: quad indices up to 543 so rows/cols 512..513 (< QN=514)
        // are written — 16x16 leaves them poisoned (R8 bug).
        prep_quads<<<dim3(17, 17), dim3(32, 8), 0, stream>>>(x, reco, Q, QT, reco_out, sino);
        proj_quad<<<dim3(6, NA, KSPLIT), dim3(128), 0, stream>>>(Q, QT, angles, sino);
    } else {
        prep_copy<<<dim3((IMG_SIZE + 255) / 256), dim3(256), 0, stream>>>(reco, reco_out);
        proj_fused<<<dim3((ND + 255) / 256, NA), dim3(256), 0, stream>>>(x, reco, angles, sino);
    }
}

// Round 12
// 147.617 us; speedup vs baseline: 1.1077x; 1.0125x over previous
//
#include <hip/hip_runtime.h>
#include <hip/hip_fp16.h>
#include <climits>

// Radon forward projection (parallel beam), 512x512 image, 512 angles,
// 736 detectors x 736 samples, bilinear interpolation.
// Outputs (flat, concatenated): sino [1,512,736] then reco [1,512,512].
//
// R12: prep parallelized 4x via grid.z (289 blocks was ~1.1/CU -> pure
//      latency-bound; non-proj gap was 46 us = 31% of total), proj packed
//      loop unroll 4 (8 loads in flight; mixed issue/latency regime).
//      Core proj structure unchanged from R11.

namespace {
constexpr int H = 512, W = 512, NA = 512, ND = 736, NS = 736;
constexpr int SINO_SIZE = NA * ND;
constexpr int IMG_SIZE = H * W;
// Quad array: entry (ri,ci), ri,ci in [0,513]:
//   q.x = (v(ri-1,ci-1), v(ri,ci-1))   column pair at ci-1
//   q.y = (v(ri-1,ci),   v(ri,ci))     column pair at ci
// zero outside [0,512)^2. Sample coords shifted +1 -> clamp domain [0,513].
constexpr int QN = 514;
constexpr int QS = 520;                 // row stride in quads (8 B each)
constexpr int QUAD_SIZE = QN * QS;
constexpr int KSPLIT = 8;
}

typedef __fp16 h2 __attribute__((ext_vector_type(2)));
typedef float  f2 __attribute__((ext_vector_type(2)));

// ---------- prep: quads + reco + sino zero; grid (17,17,4), block 32x8 -----
// Each z-slice writes 8 quad rows of the 32-row tile (t2 = ty + 8*z).
// Halo tile is reloaded per block (L2-hit cheap); 1156 blocks hide latency.
__global__ __launch_bounds__(256) void prep_quads(const float* __restrict__ x,
                                                  const float* __restrict__ reco,
                                                  uint2* __restrict__ Q,
                                                  uint2* __restrict__ QT,
                                                  float* __restrict__ reco_out,
                                                  float* __restrict__ sino) {
    __shared__ float tile[34][35];
    const int tx = threadIdx.x, ty = threadIdx.y;      // 32x8
    const int r0 = blockIdx.y * 32, c0 = blockIdx.x * 32;
    const int z  = blockIdx.z;

    // Zero sinogram (z==0 slice only; d_out is poisoned before every call).
    if (z == 0) {
        const int nthr = 289 * 256;
        const int gtid = (blockIdx.y * 17 + blockIdx.x) * 256 + ty * 32 + tx;
        for (int i = gtid; i < SINO_SIZE; i += nthr) sino[i] = 0.f;
    }

    // Load 34x34 halo tile: cell (yy,xx) = v(r0-1+yy, c0-1+xx), 0 outside.
    for (int li = ty * 32 + tx; li < 34 * 34; li += 256) {
        const int yy = li / 34, xx = li - yy * 34;
        const int r = r0 - 1 + yy, c = c0 - 1 + xx;
        float v = 0.f;
        if ((unsigned)r < 512u && (unsigned)c < 512u) {
            const int i = r * W + c;
            v = x[i] + reco[i];
        }
        tile[yy][xx] = v;
    }
    __syncthreads();

    const int t2 = ty + 8 * z;
    // Q quad (column pairs)
    const int ri = r0 + t2, ci = c0 + tx;
    if (ri < QN && ci < QN) {
        uint2 q;
        q.x = __builtin_bit_cast(unsigned int,
              __builtin_amdgcn_cvt_pkrtz(tile[t2][tx],     tile[t2 + 1][tx]));
        q.y = __builtin_bit_cast(unsigned int,
              __builtin_amdgcn_cvt_pkrtz(tile[t2][tx + 1], tile[t2 + 1][tx + 1]));
        Q[ri * QS + ci] = q;
    }
    // Transposed-image quad at transposed block location.
    const int ri2 = c0 + t2, ci2 = r0 + tx;
    if (ri2 < QN && ci2 < QN) {
        uint2 q;
        q.x = __builtin_bit_cast(unsigned int,
              __builtin_amdgcn_cvt_pkrtz(tile[tx][t2],     tile[tx][t2 + 1]));
        q.y = __builtin_bit_cast(unsigned int,
              __builtin_amdgcn_cvt_pkrtz(tile[tx + 1][t2], tile[tx + 1][t2 + 1]));
        QT[ri2 * QS + ci2] = q;
    }
    // reco pass-through (coalesced 4B/lane)
    const int rr = r0 + t2, cc = c0 + tx;
    if (rr < H && cc < W) reco_out[rr * W + cc] = reco[rr * W + cc];
}

// Per-dim k-range for p0 + k*inc in [lo, hi].
__device__ inline void range1(float p0, float inc, float lo, float hi,
                              float& klo, float& khi) {
    if (inc > 1e-6f)       { klo = (lo - p0) / inc; khi = (hi - p0) / inc; }
    else if (inc < -1e-6f) { klo = (hi - p0) / inc; khi = (lo - p0) / inc; }
    else if (p0 >= lo && p0 <= hi) { klo = -1e9f; khi = 1e9f; }
    else                   { klo = 1e9f;  khi = -1e9f; }
}

// Wave = 64 consecutive detectors, shear-mapped k; blockIdx.z = k-eighth.
__global__ __launch_bounds__(128) void proj_quad(const uint2* __restrict__ Q,
                                                 const uint2* __restrict__ QT,
                                                 const float* __restrict__ angles,
                                                 float* __restrict__ sino) {
    const int lane = threadIdx.x & 63;
    const int d = blockIdx.x * 128 + (threadIdx.x >> 6) * 64 + lane;
    const int a = blockIdx.y;
    const int z = blockIdx.z;

    float si, co;
    sincosf(angles[a], &si, &co);

    const float cx = (W - 1) * 0.5f, cy = (H - 1) * 0.5f;
    const float s  = (float)d - (ND - 1) * 0.5f;
    const float bx = fmaf(s, co, cx);    // px = bx - t*si
    const float by = fmaf(s, si, cy);    // py = by + t*c

    // Orientation: slow dim = row dim of chosen layout; |sl| >= 0.707.
    const uint2* base;
    float f0, fi, s0, sl, dS;
    if (fabsf(co) >= fabsf(si)) { base = Q;  f0 = bx; fi = -si; s0 = by; sl = co;  dS = si; }
    else                        { base = QT; f0 = by; fi = co;  s0 = bx; sl = -si; dS = co; }

    const float t0 = -(float)(NS - 1) * 0.5f;
    float F0 = fmaf(t0, fi, f0);
    float S0 = fmaf(t0, sl, s0);
    if (sl < 0.f) {   // make slow step positive (reverses sum order only)
        F0 = fmaf((float)(NS - 1), fi, F0); fi = -fi;
        S0 = fmaf((float)(NS - 1), sl, S0); sl = -sl;
    }

    // Valid k range (conservative; clamp handles boundary rounding).
    float kloF, khiF, kloS, khiS;
    range1(F0, fi, -0.9999f, 511.9999f, kloF, khiF);
    range1(S0, sl, -0.9999f, 511.9999f, kloS, khiS);
    const int kA = max(0,      (int)ceilf(fmaxf(kloF, kloS)));
    const int kB = min(NS - 1, (int)floorf(fminf(khiF, khiS)));

    // Shear offset: aligns slow coords across lanes at fixed loop index j.
    const int o = (int)rintf(-(float)lane * dS / sl);
    // +1 shift folds the pad-ring offset into the clamp domain [0, 513].
    const float F1 = fmaf((float)o, fi, F0) + 1.f;
    const float S1 = fmaf((float)o, sl, S0) + 1.f;

    int jA, jB;
    if (kA <= kB) { jA = kA - o; jB = kB - o; }
    else          { jA = INT_MAX; jB = INT_MIN; }
    int Jlo = jA, Jhi = jB;
    #pragma unroll
    for (int off = 1; off < 64; off <<= 1) {
        Jlo = min(Jlo, __shfl_xor(Jlo, off));
        Jhi = max(Jhi, __shfl_xor(Jhi, off));
    }
    if (Jlo > Jhi) return;                 // whole wave empty
    const int L  = Jhi - Jlo + 1;
    // Wave-uniform bounds -> scalar registers for scalar loop control.
    const int js = __builtin_amdgcn_readfirstlane(Jlo + (L * z) / KSPLIT);
    const int je = __builtin_amdgcn_readfirstlane(Jlo + (L * (z + 1)) / KSPLIT - 1);
    const int n  = je - js + 1;            // may be 0 for tiny L
    // Even part [js, je2], then optional single tail at je. NO overshoot:
    // overshooting je would double-count the next z-chunk's first sample.
    const int je2 = js + 2 * (n >> 1) - 1;

    const f2 fi2 = {fi, fi}, sl2 = {sl, sl};
    const f2 F12 = {F1, F1}, S12 = {S1, S1};
    f2 jf2 = {(float)js, (float)(js + 1)};
    float acc0 = 0.f, acc1 = 0.f;
    #pragma unroll 4
    for (int j = js; j <= je2; j += 2) {
        f2 pf = jf2 * fi2 + F12;           // v_pk_fma_f32
        f2 ps = jf2 * sl2 + S12;
        jf2 += (f2)2.f;
        pf = __builtin_elementwise_min(__builtin_elementwise_max(pf, (f2)0.f), (f2)513.f);
        ps = __builtin_elementwise_min(__builtin_elementwise_max(ps, (f2)0.f), (f2)513.f);
        const f2 ff = {__builtin_floorf(pf.x), __builtin_floorf(pf.y)};
        const f2 sf = {__builtin_floorf(ps.x), __builtin_floorf(ps.y)};
        const f2 fx = pf - ff;
        const f2 fy = ps - sf;
        const f2 gy = (f2)1.f - fy;
        const f2 aif = sf * (f2)520.f + ff;        // exact (< 2^24), >= 0
        const unsigned a0 = (unsigned)aif.x;       // unsigned 32-bit offset ->
        const unsigned a1 = (unsigned)aif.y;       // saddr-form global_load
        const uint2 q0 = base[a0];
        const uint2 q1 = base[a1];
        {
            const h2 l = __builtin_bit_cast(h2, q0.x);   // (v00, v10)
            const h2 r = __builtin_bit_cast(h2, q0.y);   // (v01, v11)
            const h2 fxx = __builtin_amdgcn_cvt_pkrtz(fx.x, fx.x);
            const h2 m = l + fxx * (r - l);
            const h2 wy = __builtin_amdgcn_cvt_pkrtz(gy.x, fy.x);
#if __has_builtin(__builtin_amdgcn_fdot2)
            acc0 = __builtin_amdgcn_fdot2(wy, m, acc0, false);
#else
            acc0 += (float)wy.x * (float)m.x + (float)wy.y * (float)m.y;
#endif
        }
        {
            const h2 l = __builtin_bit_cast(h2, q1.x);
            const h2 r = __builtin_bit_cast(h2, q1.y);
            const h2 fxx = __builtin_amdgcn_cvt_pkrtz(fx.y, fx.y);
            const h2 m = l + fxx * (r - l);
            const h2 wy = __builtin_amdgcn_cvt_pkrtz(gy.y, fy.y);
#if __has_builtin(__builtin_amdgcn_fdot2)
            acc1 = __builtin_amdgcn_fdot2(wy, m, acc1, false);
#else
            acc1 += (float)wy.x * (float)m.x + (float)wy.y * (float)m.y;
#endif
        }
    }
    if (n & 1) {   // single tail sample at je (scalar)
        const float jf = (float)je;
        float pf = fmaf(jf, fi, F1);
        float ps = fmaf(jf, sl, S1);
        pf = fminf(fmaxf(pf, 0.f), 513.f);
        ps = fminf(fmaxf(ps, 0.f), 513.f);
        const float ff = floorf(pf), sf = floorf(ps);
        const float fx = pf - ff,   fy = ps - sf;
        const unsigned ai = (unsigned)fmaf(sf, 520.f, ff);
        const uint2 q = base[ai];
        const h2 l = __builtin_bit_cast(h2, q.x);
        const h2 r = __builtin_bit_cast(h2, q.y);
        const h2 fxx = __builtin_amdgcn_cvt_pkrtz(fx, fx);
        const h2 m = l + fxx * (r - l);
        const h2 wy = __builtin_amdgcn_cvt_pkrtz(1.f - fy, fy);
#if __has_builtin(__builtin_amdgcn_fdot2)
        acc0 = __builtin_amdgcn_fdot2(wy, m, acc0, false);
#else
        acc0 += (float)wy.x * (float)m.x + (float)wy.y * (float)m.y;
#endif
    }
    const float acc = acc0 + acc1;
    if (d < ND)
        __hip_atomic_fetch_add(&sino[a * ND + d], acc,
                               __ATOMIC_RELAXED, __HIP_MEMORY_SCOPE_AGENT);
}

// ================= fallback (tiny ws): fused fp32 ==========================
__global__ __launch_bounds__(256) void proj_fused(const float* __restrict__ A,
                                                  const float* __restrict__ B,
                                                  const float* __restrict__ angles,
                                                  float* __restrict__ sino) {
    const int d = blockIdx.x * blockDim.x + threadIdx.x;
    const int a = blockIdx.y;
    if (d >= ND) return;
    float si, c;
    sincosf(angles[a], &si, &c);
    const float cx = (W - 1) * 0.5f, cy = (H - 1) * 0.5f;
    const float s  = (float)d - (ND - 1) * 0.5f;
    const float bx = fmaf(s, c, cx), by = fmaf(s, si, cy);
    const float t0 = -(float)(NS - 1) * 0.5f;
    float acc = 0.f;
    for (int k = 0; k < NS; ++k) {
        const float t = t0 + (float)k;
        const float px = fmaf(t, -si, bx), py = fmaf(t, c, by);
        const float x0f = floorf(px), y0f = floorf(py);
        const float fx = px - x0f, fy = py - y0f;
        const int ix = (int)x0f, iy = (int)y0f;
        auto tap = [&](int yi, int xi) -> float {
            if (xi < 0 || xi >= W || yi < 0 || yi >= H) return 0.f;
            return A[yi * W + xi] + B[yi * W + xi];
        };
        float v = 0.f;
        if (ix >= -1 && iy >= -1 && ix <= W - 1 && iy <= H - 1) {
            const float v00 = tap(iy, ix),     v01 = tap(iy, ix + 1);
            const float v10 = tap(iy + 1, ix), v11 = tap(iy + 1, ix + 1);
            const float top = fmaf(fx, v01 - v00, v00);
            const float bot = fmaf(fx, v11 - v10, v10);
            v = fmaf(fy, bot - top, top);
        }
        acc += v;
    }
    sino[a * ND + d] = acc;
}

__global__ void prep_copy(const float* __restrict__ reco, float* __restrict__ reco_out) {
    int i = blockIdx.x * blockDim.x + threadIdx.x;
    if (i < IMG_SIZE) reco_out[i] = reco[i];
}

extern "C" void kernel_launch(void* const* d_in, const int* in_sizes, int n_in,
                              void* d_out, int out_size, void* d_ws, size_t ws_size,
                              hipStream_t stream) {
    const float* x      = (const float*)d_in[0];
    const float* reco   = (const float*)d_in[1];
    const float* angles = (const float*)d_in[2];
    float* sino     = (float*)d_out;
    float* reco_out = sino + SINO_SIZE;

    const size_t need_quads = 2 * (size_t)QUAD_SIZE * sizeof(uint2);    // ~4.28 MiB

    if (ws_size >= need_quads) {
        uint2* Q  = (uint2*)d_ws;
        uint2* QT = Q + QUAD_SIZE;
        // 17x17 grid covers quad indices to 543 (QN=514 incl. pad ring);
        // z-slices split the 32 quad rows 4-way for occupancy.
        prep_quads<<<dim3(17, 17, 4), dim3(32, 8), 0, stream>>>(x, reco, Q, QT, reco_out, sino);
        proj_quad<<<dim3(6, NA, KSPLIT), dim3(128), 0, stream>>>(Q, QT, angles, sino);
    } else {
        prep_copy<<<dim3((IMG_SIZE + 255) / 256), dim3(256), 0, stream>>>(reco, reco_out);
        proj_fused<<<dim3((ND + 255) / 256, NA), dim3(256), 0, stream>>>(x, reco, angles, sino);
    }
}